// Round 5
// baseline (199.754 us; speedup 1.0000x reference)
//
#include <hip/hip_runtime.h>

// Pairlist: 2000 molecules x 64 atoms, ordered intra-molecule pairs.
// Out (flat f32): i[P], j[P], d[P], r_ij[P*3]; P = 8,064,000. Write-bound.
// R5: 3 chunks (3072 consecutive pairs) per block -> 2625 blocks instead of
// 7875. A 3072-pair span covers <=2 molecules, so positions staged ONCE with
// ONE barrier; 3 barrier-free chunk iterations (wave-local LDS r-transpose,
// per-wave in-order DS makes rbuf reuse safe). Tests the per-block-overhead
// hypothesis (CP launch + staging + barrier + wave ramp were 1/3 of cost?).

#define N_MOL   2000
#define MOL_A   64
#define PPM     (MOL_A * (MOL_A - 1))    // 4032 pairs / molecule
#define P_TOTAL (N_MOL * PPM)            // 8,064,000
#define BLOCK   256
#define PPB     1024                     // pairs per chunk (4 per thread)
#define CHUNKS  3                        // chunks per block
#define BLOCKS  (P_TOTAL / (PPB * CHUNKS))  // 2625 exact

typedef float f4 __attribute__((ext_vector_type(4)));

__global__ __launch_bounds__(BLOCK) void Pairlist_54932631716418_kernel(
    const float* __restrict__ pos, float* __restrict__ out) {
  __shared__ float posb[128 * 4];          // 2 molecules, 4 words/atom (2 KB)
  __shared__ float rbuf[4][3][256];        // per-wave SoA rx/ry/rz (12 KB)

  const int t  = threadIdx.x;
  const int L  = t & 63;                   // lane
  const int w  = t >> 6;                   // wave id in block
  const int PB = blockIdx.x * (PPB * CHUNKS);  // first pair of this block
  const int mf = PB / PPM;                 // first molecule (block spans <= 2)

  // ---- stage 2 molecules, padded to 4 words/atom (once per block) ----
  {
    const int gmax = N_MOL * MOL_A * 3 - 1;
    const int g0   = mf * (MOL_A * 3);
    int v = t;                             // source word 0..383
    int a = g0 + v; if (a > gmax) a = gmax;
    float x = pos[a];
    posb[(v / 3) * 4 + (v - (v / 3) * 3)] = x;
    v = t + BLOCK;
    if (v < 384) {
      int a1 = g0 + v; if (a1 > gmax) a1 = gmax;
      float x1 = pos[a1];
      posb[(v / 3) * 4 + (v - (v / 3) * 3)] = x1;
    }
  }
  __syncthreads();                         // the ONLY barrier

  const int baseAtom = mf * MOL_A;

#pragma unroll
  for (int c = 0; c < CHUNKS; ++c) {
    const int P0 = PB + c * PPB;
    const int p0 = P0 + 4 * t;             // 4 pairs, single molecule (4032%4==0)
    int rp      = p0 - mf * PPM;
    int atomOff = 0;
    int base    = baseAtom;
    if (rp >= PPM) { rp -= PPM; atomOff = 64; base += MOL_A; }

    float fi[4], fj[4], fd[4];
    f4 rx, ry, rz;
#pragma unroll
    for (int s = 0; s < 4; ++s) {
      const int r = rp + s;
      const int i = r / 63;                // magic-mul
      const int k = r - 63 * i;
      const int j = k + (k >= i ? 1 : 0);
      const f4 pi = *(const f4*)(posb + 4 * (atomOff + i));  // ds_read_b128
      const f4 pj = *(const f4*)(posb + 4 * (atomOff + j));  // ds_read_b128
      const float dx = pj.x - pi.x, dy = pj.y - pi.y, dz = pj.z - pi.z;
      fi[s] = (float)(base + i);
      fj[s] = (float)(base + j);
      fd[s] = sqrtf(dx * dx + dy * dy + dz * dz);
      ((float*)&rx)[s] = dx; ((float*)&ry)[s] = dy; ((float*)&rz)[s] = dz;
    }

    // wave-local SoA staging; per-wave in-order DS pipe => no barrier, and
    // WAR vs previous chunk's reads is safe.
    *(f4*)&rbuf[w][0][4 * L] = rx;
    *(f4*)&rbuf[w][1][4 * L] = ry;
    *(f4*)&rbuf[w][2][4 * L] = rz;

    const float* rb = &rbuf[w][0][0];
    f4 rv[3];
#pragma unroll
    for (int s = 0; s < 3; ++s) {
#pragma unroll
      for (int u = 0; u < 4; ++u) {
        const int F = 256 * s + 4 * L + u; // wave-local r-stream float index
        const int q = F / 3;               // magic-mul
        const int cc = F - 3 * q;
        ((float*)&rv[s])[u] = rb[256 * cc + q];
      }
    }

    // ---- global stores for this chunk, nontemporal, lane-contiguous ----
    __builtin_nontemporal_store((f4){fi[0], fi[1], fi[2], fi[3]},
                                (f4*)(out + p0));
    __builtin_nontemporal_store((f4){fj[0], fj[1], fj[2], fj[3]},
                                (f4*)(out + P_TOTAL + p0));
    __builtin_nontemporal_store((f4){fd[0], fd[1], fd[2], fd[3]},
                                (f4*)(out + 2 * P_TOTAL + p0));
    float* outr = out + 3 * (size_t)P_TOTAL + 3 * (size_t)P0;
#pragma unroll
    for (int s = 0; s < 3; ++s) {
      const int g = 192 * w + 64 * s + L;  // wave-local output f4 index
      __builtin_nontemporal_store(rv[s], (f4*)(outr + 4 * g));
    }
  }
}

extern "C" void kernel_launch(void* const* d_in, const int* in_sizes, int n_in,
                              void* d_out, int out_size, void* d_ws, size_t ws_size,
                              hipStream_t stream) {
  const float* pos = (const float*)d_in[0];   // positions [128000, 3] f32
  float* out = (float*)d_out;
  Pairlist_54932631716418_kernel<<<BLOCKS, BLOCK, 0, stream>>>(pos, out);
}